// Round 1
// 596.966 us; speedup vs baseline: 1.0686x; 1.0686x over previous
//
#include <hip/hip_runtime.h>

#define VOCAB 8000
#define HIDDEN 256
#define BATCH 32
#define SEQ 256
#define NPAD 8192              // 32 * 256, zero-padded vocab for GEMM staging
#define MROWS (SEQ * BATCH)    // 8192
#define HSTR 264               // LDS row stride in shorts (rnn H buffer)
#define NCONS 126              // consumer (gemm) blocks; total grid = 128 <= 256 CUs
#define TM_TILES (MROWS / 128) // 64
#define TN_TILES (NPAD / 256)  // 32
#define TRB 2000               // transpose tile blocks: (VOCAB/32)*(HIDDEN/32)

typedef __attribute__((ext_vector_type(8))) short short8;   // 8 bf16 (4 VGPRs)
typedef __attribute__((ext_vector_type(4))) short short4v;  // 4 bf16 (8B)
typedef __attribute__((ext_vector_type(4))) float floatx4;  // 4 f32 acc

// ---------- helpers ----------

__device__ __forceinline__ void async_copy16(const void* g, void* l) {
    __builtin_amdgcn_global_load_lds(
        (const __attribute__((address_space(1))) unsigned int*)g,
        (__attribute__((address_space(3))) unsigned int*)l, 16, 0, 0);
}

__device__ __forceinline__ unsigned short f32_to_bf16(float f) {
    unsigned int u = __float_as_uint(f);
    unsigned int lsb = (u >> 16) & 1u;
    u += 0x7fffu + lsb;            // round-to-nearest-even
    return (unsigned short)(u >> 16);
}

__device__ __forceinline__ float bf16_to_f32(unsigned short u) {
    return __uint_as_float(((unsigned int)u) << 16);
}

// ---------- kernel 1 (prep): W_ih transpose -> W_ihT, W_out f32 -> bf16 padded, zero progress ----------

__global__ void __launch_bounds__(256) prep_kernel(const float* __restrict__ W_ih,
                                                   float* __restrict__ W_ihT,
                                                   const float* __restrict__ W_out,
                                                   unsigned short* __restrict__ Wbf,
                                                   int* __restrict__ progress) {
    const int bid = blockIdx.x;
    if (bid < TRB) {
        if (bid == 0 && threadIdx.x == 0) *progress = 0;   // reset flag each replay
        __shared__ float tile[32][33];
        const int tv = (bid % 250) * 32;     // vocab tile
        const int th = (bid / 250) * 32;     // hidden tile
        const int tx = threadIdx.x & 31;
        const int ty = threadIdx.x >> 5;     // 0..7
#pragma unroll
        for (int k = 0; k < 4; ++k)          // coalesced read along vocab
            tile[ty + 8 * k][tx] = W_ih[(size_t)(th + ty + 8 * k) * VOCAB + tv + tx];
        __syncthreads();
#pragma unroll
        for (int k = 0; k < 4; ++k)          // coalesced write along hidden
            W_ihT[(size_t)(tv + ty + 8 * k) * HIDDEN + th + tx] = tile[tx][ty + 8 * k];
    } else {
        const int v = bid - TRB;             // 0..NPAD-1
        const int k = threadIdx.x;
        float f = (v < VOCAB) ? W_out[(size_t)v * HIDDEN + k] : 0.0f;
        Wbf[(size_t)v * HIDDEN + k] = f32_to_bf16(f);
    }
}

// ---------- fused kernel: blocks 0,1 = Elman recurrence (producer); blocks 2.. = out-GEMM (consumer) ----------
// Producer: unchanged proven v3 math; x_t gathered inline from W_ihT[tok] (prefetched 1 step ahead);
//           b_ih folded into bias; publishes progress (release, agent) every 8 steps.
// Consumer: m-tile t needs steps 4t..4t+3 -> waits for progress >= 2*((t>>1)+1) via relaxed poll,
//           then ONE acquire fence (buffer_inv) per new chunk. 128x256 tile, 8 waves (2x4), 64x64/wave.

__device__ __forceinline__ void rnn_role(const float* __restrict__ W_ihT,
                                         const int* __restrict__ X,
                                         const float* __restrict__ h0,
                                         const float* __restrict__ W_hh,
                                         const float* __restrict__ b_hh,
                                         const float* __restrict__ b_ih,
                                         unsigned short* __restrict__ Ybf,
                                         float* __restrict__ h_last,
                                         int* __restrict__ progress,
                                         char* smem) {
    unsigned short (*Hh)[16 * HSTR] = (unsigned short (*)[16 * HSTR])smem;

    const int tid  = threadIdx.x;
    const int lane = tid & 63;
    const int w    = tid >> 6;       // wave 0..7 -> i-range [32w, 32w+32)
    const int l16  = lane & 15;      // A: i row-in-tile; B/C: batch col
    const int lq   = lane >> 4;      // 0..3
    const int bg0  = blockIdx.x * 16;

    // ---- load + split W_hh A-fragments (hi/lo bf16) ----
    short8 Whi[2][8], Wlo[2][8];
#pragma unroll
    for (int t = 0; t < 2; ++t) {
#pragma unroll
        for (int c = 0; c < 8; ++c) {
            const float* p = W_hh + (size_t)(32 * w + 16 * t + l16) * HIDDEN + 32 * c + 8 * lq;
            float4 f0 = *(const float4*)p;
            float4 f1 = *(const float4*)(p + 4);
            float v[8] = {f0.x, f0.y, f0.z, f0.w, f1.x, f1.y, f1.z, f1.w};
            short8 hi, lo;
#pragma unroll
            for (int e = 0; e < 8; ++e) {
                unsigned short h16 = f32_to_bf16(v[e]);
                hi[e] = (short)h16;
                lo[e] = (short)f32_to_bf16(v[e] - bf16_to_f32(h16));
            }
            Whi[t][c] = hi;
            Wlo[t][c] = lo;
        }
    }

    float4 bhh[2];   // (b_hh + b_ih)[i], i = 32w + 16t + 4lq + r
#pragma unroll
    for (int t = 0; t < 2; ++t) {
        float4 a = *(const float4*)(b_hh + 32 * w + 16 * t + 4 * lq);
        float4 b = *(const float4*)(b_ih + 32 * w + 16 * t + 4 * lq);
        bhh[t].x = a.x + b.x; bhh[t].y = a.y + b.y;
        bhh[t].z = a.z + b.z; bhh[t].w = a.w + b.w;
    }

    // ---- init H buffer 0 from h0 ----
    {
        int b  = tid >> 5;            // 0..15
        int k0 = (tid & 31) * 8;      // 8 consecutive k
#pragma unroll
        for (int k = 0; k < 8; ++k)
            Hh[0][b * HSTR + k0 + k] = f32_to_bf16(h0[(size_t)(bg0 + b) * HIDDEN + k0 + k]);
    }

    // prefetch x for step 0: x[b = l16][i] = W_ihT[tok][i]
    const int xrow = (bg0 + l16) * SEQ;
    float4 xbuf[2];
    {
        int tok = X[xrow];
#pragma unroll
        for (int t = 0; t < 2; ++t)
            xbuf[t] = *(const float4*)(W_ihT + (size_t)tok * HIDDEN + 32 * w + 16 * t + 4 * lq);
    }

    __syncthreads();

#pragma unroll 1
    for (int s = 0; s < SEQ; ++s) {
        const unsigned short* Hc = Hh[s & 1];
        unsigned short*       Hn = Hh[(s & 1) ^ 1];

        short8 hb[8];
#pragma unroll
        for (int c = 0; c < 8; ++c)
            hb[c] = *(const short8*)&Hc[l16 * HSTR + 32 * c + 8 * lq];

        floatx4 a1[2], a2[2];
#pragma unroll
        for (int t = 0; t < 2; ++t) {
            a1[t][0] = xbuf[t].x + bhh[t].x;
            a1[t][1] = xbuf[t].y + bhh[t].y;
            a1[t][2] = xbuf[t].z + bhh[t].z;
            a1[t][3] = xbuf[t].w + bhh[t].w;
            a2[t][0] = a2[t][1] = a2[t][2] = a2[t][3] = 0.f;
        }

        // prefetch next x (token -> W_ihT row), hidden under MFMAs
        if (s + 1 < SEQ) {
            int tok = X[xrow + s + 1];
#pragma unroll
            for (int t = 0; t < 2; ++t)
                xbuf[t] = *(const float4*)(W_ihT + (size_t)tok * HIDDEN + 32 * w + 16 * t + 4 * lq);
        }

        // 32 MFMAs: 4 independent chains, 8 deep each
#pragma unroll
        for (int c = 0; c < 8; ++c) {
            a1[0] = __builtin_amdgcn_mfma_f32_16x16x32_bf16(Whi[0][c], hb[c], a1[0], 0, 0, 0);
            a1[1] = __builtin_amdgcn_mfma_f32_16x16x32_bf16(Whi[1][c], hb[c], a1[1], 0, 0, 0);
            a2[0] = __builtin_amdgcn_mfma_f32_16x16x32_bf16(Wlo[0][c], hb[c], a2[0], 0, 0, 0);
            a2[1] = __builtin_amdgcn_mfma_f32_16x16x32_bf16(Wlo[1][c], hb[c], a2[1], 0, 0, 0);
        }

        // epilogue: tanh, pack bf16, write H[next] + Y
#pragma unroll
        for (int t = 0; t < 2; ++t) {
            const int i0 = 32 * w + 16 * t + 4 * lq;
            float hn[4];
            short4v hi4;
#pragma unroll
            for (int r = 0; r < 4; ++r) {
                float a  = a1[t][r] + a2[t][r];
                float e  = __builtin_amdgcn_exp2f(a * 2.88539004f);
                float rc = __builtin_amdgcn_rcpf(e + 1.0f);
                hn[r] = fmaf(-2.0f, rc, 1.0f);
                hi4[r] = (short)f32_to_bf16(hn[r]);
            }
            *(short4v*)&Hn[l16 * HSTR + i0] = hi4;
            *(short4v*)(Ybf + (size_t)(s * BATCH + bg0 + l16) * HIDDEN + i0) = hi4;
            if (s == SEQ - 1) {
#pragma unroll
                for (int r = 0; r < 4; ++r)
                    h_last[(size_t)(bg0 + l16) * HIDDEN + i0 + r] = hn[r];
            }
        }
        __syncthreads();   // drains vmcnt: all waves' Y stores complete before publish

        // publish every 8 steps: release flushes this XCD's dirty Y lines to LLC
        if (((s & 7) == 7) && tid == 0)
            __hip_atomic_fetch_add(progress, 1, __ATOMIC_RELEASE, __HIP_MEMORY_SCOPE_AGENT);
    }
}

__device__ __forceinline__ void gemm_role(const unsigned short* __restrict__ Ybf,
                                          const unsigned short* __restrict__ Wbf,
                                          const float* __restrict__ b_out,
                                          float* __restrict__ out,
                                          int* __restrict__ progress,
                                          char* smem) {
    short* sA = (short*)smem;                    // [128][32]
    short* sB = (short*)(smem + 128 * 32 * 2);   // [256][32]

    const int tid  = threadIdx.x;
    const int lane = tid & 63;
    const int wave = tid >> 6;
    const int wm   = wave >> 2;      // 0..1 (M)
    const int wn   = wave & 3;       // 0..3 (N)
    const int l16  = lane & 15;
    const int lq   = lane >> 4;
    const int cid  = blockIdx.x - 2;

    int fenced = 0;   // highest progress level already acquire-fenced (tid 0 only)

    for (int T = cid; T < TM_TILES * TN_TILES; T += NCONS) {
        const int tm = T >> 5;       // T / TN_TILES  (m-tile; monotone increasing per block)
        const int tn = T & 31;
        const int m0 = tm * 128;
        const int n0 = tn * 256;

        if (tid == 0) {
            const int need = 2 * ((tm >> 1) + 1);   // both producers past 8-step chunk (tm>>1)
            if (need > fenced) {
                while (__hip_atomic_load(progress, __ATOMIC_RELAXED, __HIP_MEMORY_SCOPE_AGENT) < need)
                    __builtin_amdgcn_s_sleep(8);
                __builtin_amdgcn_fence(__ATOMIC_ACQUIRE, "agent");  // one buffer_inv per chunk
                fenced = need;
            }
        }
        __syncthreads();

        floatx4 acc[4][4] = {};

        const int rA  = tid >> 2, kcA = tid & 3;   // A: 512 16B-chunks
        const int c1  = tid + 512;                 // B: 1024 16B-chunks
        const int rB1 = c1 >> 2,  kB1 = c1 & 3;

        for (int k0 = 0; k0 < HIDDEN; k0 += 32) {
            async_copy16(Ybf + (size_t)(m0 + rA) * HIDDEN + k0 + kcA * 8, sA + tid * 8);
            async_copy16(Wbf + (size_t)(n0 + rA) * HIDDEN + k0 + kcA * 8, sB + tid * 8);
            async_copy16(Wbf + (size_t)(n0 + rB1) * HIDDEN + k0 + kB1 * 8, sB + c1 * 8);
            __syncthreads();

            short8 af[4], bfr[4];
#pragma unroll
            for (int t = 0; t < 4; ++t) {
                af[t]  = *(const short8*)&sA[(wm * 64 + t * 16 + l16) * 32 + lq * 8];
                bfr[t] = *(const short8*)&sB[(wn * 64 + t * 16 + l16) * 32 + lq * 8];
            }
#pragma unroll
            for (int a = 0; a < 4; ++a)
#pragma unroll
                for (int b = 0; b < 4; ++b)
                    acc[a][b] = __builtin_amdgcn_mfma_f32_16x16x32_bf16(
                        af[a], bfr[b], acc[a][b], 0, 0, 0);
            __syncthreads();
        }

#pragma unroll
        for (int tn4 = 0; tn4 < 4; ++tn4) {
            int n = n0 + wn * 64 + tn4 * 16 + l16;
            if (n < VOCAB) {
                float bo = b_out[n];
#pragma unroll
                for (int tm4 = 0; tm4 < 4; ++tm4) {
                    int mbase = m0 + wm * 64 + tm4 * 16 + lq * 4;
#pragma unroll
                    for (int r = 0; r < 4; ++r)
                        __builtin_nontemporal_store(acc[tm4][tn4][r] + bo,
                            &out[(size_t)(mbase + r) * VOCAB + n]);
                }
            }
        }
    }
}

__global__ void __launch_bounds__(512, 2) fused_kernel(const float* __restrict__ W_ihT,
                                                       const int* __restrict__ X,
                                                       const float* __restrict__ h0,
                                                       const float* __restrict__ W_hh,
                                                       const float* __restrict__ b_hh,
                                                       const float* __restrict__ b_ih,
                                                       unsigned short* __restrict__ Ybf,
                                                       float* __restrict__ h_last,
                                                       const unsigned short* __restrict__ Wbf,
                                                       const float* __restrict__ b_out,
                                                       float* __restrict__ out,
                                                       int* __restrict__ progress) {
    __shared__ __align__(16) char smem[24576];   // max(rnn 16896, gemm 24576)
    if (blockIdx.x < 2)
        rnn_role(W_ihT, X, h0, W_hh, b_hh, b_ih, Ybf, h_last, progress, smem);
    else
        gemm_role(Ybf, Wbf, b_out, out, progress, smem);
}

// ---------- launch ----------

extern "C" void kernel_launch(void* const* d_in, const int* in_sizes, int n_in,
                              void* d_out, int out_size, void* d_ws, size_t ws_size,
                              hipStream_t stream) {
    const int*   X     = (const int*)d_in[0];
    const float* h0    = (const float*)d_in[1];
    const float* W_ih  = (const float*)d_in[2];
    const float* b_ih  = (const float*)d_in[3];
    const float* W_hh  = (const float*)d_in[4];
    const float* b_hh  = (const float*)d_in[5];
    const float* W_out = (const float*)d_in[6];
    const float* b_out = (const float*)d_in[7];

    float* out    = (float*)d_out;
    float* h_last = out + (size_t)MROWS * VOCAB;

    char* ws = (char*)d_ws;
    float*          W_ihT    = (float*)ws;                         // 8,192,000 B
    unsigned short* Ybf      = (unsigned short*)(ws + 8192000);    // 4,194,304 B
    unsigned short* Wbf      = (unsigned short*)(ws + 12386304);   // 4,194,304 B
    int*            progress = (int*)(ws + 16580608);              // 4 B

    hipLaunchKernelGGL(prep_kernel, dim3(TRB + NPAD), dim3(256), 0, stream,
                       W_ih, W_ihT, W_out, Wbf, progress);
    hipLaunchKernelGGL(fused_kernel, dim3(2 + NCONS), dim3(512), 0, stream,
                       W_ihT, X, h0, W_hh, b_hh, b_ih, Ybf, h_last, Wbf, b_out, out, progress);
}